// Round 2
// baseline (498.656 us; speedup 1.0000x reference)
//
#include <hip/hip_runtime.h>

// LIF scan: z [B=32, T=1024, H=512] fp32 -> out [32,1024,512] fp32
//   V_t = 0.9*V_{t-1} + z[:,t-1,:] - (V_{t-1} > 1)          (exact fp32 op order)
//   out[:,t,:] = (V_t > 1) ? 1 : 0,  out[:,0,:] = 0
// One thread per (b,h) chain: 16384 threads = 256 waves (1/CU). Memory-
// latency-bound stream. Round-1 lesson: non-volatile prefetch loads get
// rematerialized at their use (VGPR_Count=36 proved the 31-deep pipeline was
// deleted). Fix: volatile z loads pin issue order & forbid remat -> 31 loads
// genuinely outstanding per wave (2.0 MB chip-wide ~ HBM BDP), and
// __launch_bounds__(64,1) grants the 512-VGPR budget so the scheduler doesn't
// optimize for occupancy we can't use anyway.

#define LIF_B 32
#define LIF_T 1024
#define LIF_H 512
#define LIF_S 1023   // time steps
#define LIF_P 31     // prefetch depth; 31 * 33 == 1023

__global__ __launch_bounds__(64, 1) void lif_kernel(const float* __restrict__ z,
                                                    float* __restrict__ out) {
    const int n = blockIdx.x * blockDim.x + threadIdx.x;   // 0..16383
    const int b = n >> 9;                                  // n / 512
    const int h = n & (LIF_H - 1);                         // n % 512
    const int base = b * (LIF_T * LIF_H) + h;              // element index of z[b,0,h]

    // volatile: loads cannot be rematerialized/reordered w.r.t. each other
    const volatile float* zv = z;

    out[base] = 0.0f;                                      // t = 0 row stays zero

    float buf[LIF_P];
#pragma unroll
    for (int i = 0; i < LIF_P; ++i)
        buf[i] = zv[base + i * LIF_H];

    float V = 0.0f;
    int t = 0;
    // 32 full blocks with prefetch (covers t = 0..991, prefetches up to t=1022)
    for (int blk = 0; blk < 32; ++blk) {
#pragma unroll
        for (int i = 0; i < LIF_P; ++i) {
            const float zvv = buf[i];
            buf[i] = zv[base + (t + LIF_P) * LIF_H];       // prefetch t+31 (volatile)
            // exact reference op order: (0.9*V + z) - reset ; no FMA contraction
            const float v0 = __fadd_rn(__fmul_rn(0.9f, V), zvv);
            const float Vn = (V > 1.0f) ? __fsub_rn(v0, 1.0f) : v0;
            out[base + (t + 1) * LIF_H] = (Vn > 1.0f) ? 1.0f : 0.0f;
            V = Vn;
            ++t;
        }
    }
    // tail block, no prefetch (t = 992..1022)
#pragma unroll
    for (int i = 0; i < LIF_P; ++i) {
        const float zvv = buf[i];
        const float v0 = __fadd_rn(__fmul_rn(0.9f, V), zvv);
        const float Vn = (V > 1.0f) ? __fsub_rn(v0, 1.0f) : v0;
        out[base + (t + 1) * LIF_H] = (Vn > 1.0f) ? 1.0f : 0.0f;
        V = Vn;
        ++t;
    }
}

extern "C" void kernel_launch(void* const* d_in, const int* in_sizes, int n_in,
                              void* d_out, int out_size, void* d_ws, size_t ws_size,
                              hipStream_t stream) {
    const float* z = (const float*)d_in[0];
    float* out = (float*)d_out;
    const int total = LIF_B * LIF_H;                       // 16384 chains
    dim3 block(64);
    dim3 grid(total / 64);                                 // 256 blocks -> all 256 CUs
    hipLaunchKernelGGL(lif_kernel, grid, block, 0, stream, z, out);
}

// Round 3
// 118.232 us; speedup vs baseline: 4.2176x; 4.2176x over previous
//
#include <hip/hip_runtime.h>

// LIF scan: z [B=32, T=1024, H=512] fp32 -> out [32,1024,512] fp32
//   V_t = 0.9*V_{t-1} + z[:,t-1,:] - (V_{t-1} > 1)      (exact fp32 op order)
//   out[:,t,:] = (V_t > 1) ? 1 : 0,  out[:,0,:] = 0
//
// One thread per (b,h) chain: 16384 threads = 256 waves (1 wave/CU).
// Memory-latency-bound stream; the only lever is per-wave load ILP.
//   R1 lesson: plain prefetch ring gets deleted by the pre-RA scheduler
//     (VGPR=36) -> ~10 loads in flight, 57 us.
//   R2 lesson: volatile = s_waitcnt vmcnt(0) per load -> 970 cyc/step, 414 us.
// Fix: explicit register double-buffer (bufA/bufB, 31 steps each), phases
// fenced with __builtin_amdgcn_sched_barrier(0) so the scheduler cannot sink
// loads into the compute phase, and __launch_bounds__(64,1) so it has the
// full 512-VGPR budget (occupancy >1 wave/SIMD is useless here anyway).
// 33 chunks of 31 steps = 1023; outer loop does 16 A/B pairs + tail chunk.

#define LIF_H 512
#define LIF_C 31     // chunk length; 33*31 = 1023 steps

__global__ __launch_bounds__(64, 1) void lif_kernel(const float* __restrict__ z,
                                                    float* __restrict__ out) {
    const int n = blockIdx.x * 64 + threadIdx.x;       // 0..16383
    const int b = n >> 9;                              // n / 512
    const int h = n & (LIF_H - 1);                     // n % 512
    const int base = b * (1024 * LIF_H) + h;

    const float* zp = z + base;                        // z[b, s, h]   = zp[s*512]
    float* op = out + base + LIF_H;                    // out[b, s+1, h] = op[s*512]

    out[base] = 0.0f;                                  // t = 0 row stays zero

    float bufA[LIF_C], bufB[LIF_C];
    float V = 0.0f;

    // preload chunk 0 into A
#pragma unroll
    for (int i = 0; i < LIF_C; ++i) bufA[i] = zp[i * LIF_H];
    __builtin_amdgcn_sched_barrier(0);

    for (int p = 0; p < 16; ++p) {
        const int c0 = 2 * p;                          // chunk held in A

        // ---- load chunk c0+1 into B (31 independent loads) ----
#pragma unroll
        for (int i = 0; i < LIF_C; ++i)
            bufB[i] = zp[((c0 + 1) * LIF_C + i) * LIF_H];
        __builtin_amdgcn_sched_barrier(0);

        // ---- compute chunk c0 from A ----
#pragma unroll
        for (int i = 0; i < LIF_C; ++i) {
            const int s = c0 * LIF_C + i;
            const float v0 = __fadd_rn(__fmul_rn(0.9f, V), bufA[i]);
            const float Vn = (V > 1.0f) ? __fsub_rn(v0, 1.0f) : v0;
            op[s * LIF_H] = (Vn > 1.0f) ? 1.0f : 0.0f;
            V = Vn;
        }
        __builtin_amdgcn_sched_barrier(0);

        // ---- load chunk c0+2 into A ----
#pragma unroll
        for (int i = 0; i < LIF_C; ++i)
            bufA[i] = zp[((c0 + 2) * LIF_C + i) * LIF_H];
        __builtin_amdgcn_sched_barrier(0);

        // ---- compute chunk c0+1 from B ----
#pragma unroll
        for (int i = 0; i < LIF_C; ++i) {
            const int s = (c0 + 1) * LIF_C + i;
            const float v0 = __fadd_rn(__fmul_rn(0.9f, V), bufB[i]);
            const float Vn = (V > 1.0f) ? __fsub_rn(v0, 1.0f) : v0;
            op[s * LIF_H] = (Vn > 1.0f) ? 1.0f : 0.0f;
            V = Vn;
        }
        __builtin_amdgcn_sched_barrier(0);
    }

    // tail: chunk 32 from A (loaded in the last pair iteration), no prefetch
#pragma unroll
    for (int i = 0; i < LIF_C; ++i) {
        const int s = 32 * LIF_C + i;
        const float v0 = __fadd_rn(__fmul_rn(0.9f, V), bufA[i]);
        const float Vn = (V > 1.0f) ? __fsub_rn(v0, 1.0f) : v0;
        op[s * LIF_H] = (Vn > 1.0f) ? 1.0f : 0.0f;
        V = Vn;
    }
}

extern "C" void kernel_launch(void* const* d_in, const int* in_sizes, int n_in,
                              void* d_out, int out_size, void* d_ws, size_t ws_size,
                              hipStream_t stream) {
    const float* z = (const float*)d_in[0];
    float* out = (float*)d_out;
    dim3 block(64);
    dim3 grid((32 * LIF_H) / 64);                      // 256 blocks -> all 256 CUs
    hipLaunchKernelGGL(lif_kernel, grid, block, 0, stream, z, out);
}